// Round 4
// baseline (263.800 us; speedup 1.0000x reference)
//
#include <hip/hip_runtime.h>

// CIN fused 3-layer, bf16 MFMA, barrier-free K-loop version.
// cur[sl,n] = sum_f x_f[sl] * S_f[sl,n],  S_f = sum_g h_g[sl] * W[f*64+g, n].
// Wave w (0..7) owns n-tile w (16 channels) and ALL 4 m-tiles (64 slices);
// B-frags are wave-private -> streamed L2->VGPR with global_load_dwordx4,
// depth-2 register rotation, NO barrier inside the f-loop (h/x read-only in
// LDS; A-frags hoisted to registers per layer). Per-CU B traffic 16KB/tile.
//
// wt layout (prep output, same as R3), tile tl = l*39+f (layer0 g zero-padded):
//   wt[tl*8192 + ((ks*4 + q)*128 + n)*8 + j] = bf16(W_l[f*64 + ks*32+q*8+j][n])

#define NF     39
#define LCH    128
#define NLAYER 3
#define NFT    (NLAYER * NF)   // 117 f-tiles

typedef __bf16        bf16x8 __attribute__((ext_vector_type(8)));
typedef unsigned int  uint4v __attribute__((ext_vector_type(4)));
typedef float         f32x4  __attribute__((ext_vector_type(4)));

__device__ __forceinline__ unsigned short f2bf_rne(float f) {
    unsigned u = __float_as_uint(f);
    u += 0x7fffu + ((u >> 16) & 1u);
    return (unsigned short)(u >> 16);
}

// ---------------- prep: W fp32 -> bf16 frag-ready tiles in ws ----------------
__global__ void cin_prep(const float* __restrict__ W0,
                         const float* __restrict__ W1,
                         const float* __restrict__ W2,
                         unsigned short* __restrict__ wt)
{
    const int t = blockIdx.x * blockDim.x + threadIdx.x; // ((tl*2+ks)*4+q)*128 + n
    if (t >= NFT * 1024) return;
    const int n  = t & 127;
    const int q  = (t >> 7) & 3;
    const int ks = (t >> 9) & 1;
    const int tl = t >> 10;
    const int l  = tl / NF;
    const int f  = tl - l * NF;
    const float* W = (l == 0) ? W0 : (l == 1) ? W1 : W2;

    unsigned short v[8];
    #pragma unroll
    for (int j = 0; j < 8; ++j) {
        const int g = ks * 32 + q * 8 + j;
        float w = 0.0f;
        if (l == 0) { if (g < NF) w = W[(f * NF + g) * LCH + n]; }
        else        { w = W[(f * 64 + g) * LCH + n]; }
        v[j] = f2bf_rne(w);
    }
    uint4v pv;
    #pragma unroll
    for (int i = 0; i < 4; ++i)
        pv[i] = (unsigned)v[2 * i] | ((unsigned)v[2 * i + 1] << 16);
    ((uint4v*)wt)[t] = pv;   // 16B coalesced
}

// ---------------- main ----------------
__global__ __launch_bounds__(512) void cin_mfma(
    const float* __restrict__ x,
    const unsigned short* __restrict__ wt,
    const float* __restrict__ b0p,
    const float* __restrict__ b1p,
    const float* __restrict__ b2p,
    float* __restrict__ out)
{
    __shared__ __align__(16) unsigned short hfrag[8 * 64 * 8];  // [gblk][sl][j], 8 KB
    __shared__ float xf32[NF * 64];                             // [f][sl] fp32
    __shared__ float biasl[NLAYER * LCH];

    const int tid  = threadIdx.x;
    const int lane = tid & 63;
    const int w    = tid >> 6;      // wave 0..7 = n-tile
    const int q    = lane >> 4;     // quad 0..3
    const int c    = lane & 15;
    const int nc   = w * 16 + c;    // this lane's output channel
    const int bb   = blockIdx.x * 4;

    // zero hfrag (covers layer-0 padding g in [39,64))
    {
        f32x4 z = {0.f, 0.f, 0.f, 0.f};
        ((f32x4*)hfrag)[tid] = z;   // 512*16B = 8 KB exactly
    }
    for (int t = tid; t < NLAYER * LCH; t += 512)
        biasl[t] = (t < 128) ? b0p[t] : (t < 256) ? b1p[t - 128] : b2p[t - 256];
    __syncthreads();

    // stage x (contiguous 2496 floats for this block's 4 b's)
    for (int i = tid; i < 4 * NF * 16; i += 512) {
        const float v = x[bb * (NF * 16) + i];
        const int lb = i / (NF * 16);
        const int r  = i - lb * (NF * 16);
        const int f  = r >> 4;
        const int d  = r & 15;
        const int sl = lb * 16 + d;
        xf32[f * 64 + sl] = v;
        hfrag[((f >> 3) * 64 + sl) * 8 + (f & 7)] = f2bf_rne(v);
    }

    // wave-private B pointer: lane (q,c) of wave w reads 16B at
    // wt + tl*8192 + (q*128 + nc)*8  (ks=0)  and +4096 shorts (ks=1)
    const unsigned short* wq = wt + (q * 128 + nc) * 8;

    // depth-2 register rotation, preloaded before the barrier (regs only)
    bf16x8 pre0[2], pre1[2];
    {
        const unsigned short* p0 = wq;             // tl = 0
        const unsigned short* p1 = wq + 8192;      // tl = 1
        pre0[0] = *(const bf16x8*)p0;  pre1[0] = *(const bf16x8*)(p0 + 4096);
        pre0[1] = *(const bf16x8*)p1;  pre1[1] = *(const bf16x8*)(p1 + 4096);
    }
    __syncthreads();   // x, hfrag, bias ready

    #pragma unroll
    for (int l = 0; l < NLAYER; ++l) {
        // hoist A-frags (h) for this layer: a[ks][mt]
        bf16x8 a[2][4];
        #pragma unroll
        for (int ks = 0; ks < 2; ++ks)
            #pragma unroll
            for (int mt = 0; mt < 4; ++mt)
                a[ks][mt] = *(const bf16x8*)&hfrag[((ks * 4 + q) * 64 + mt * 16 + c) * 8];

        f32x4 cur[4];
        #pragma unroll
        for (int mt = 0; mt < 4; ++mt) cur[mt] = f32x4{0.f, 0.f, 0.f, 0.f};
        const f32x4 z = {0.f, 0.f, 0.f, 0.f};

        #pragma unroll 2
        for (int f = 0; f < NF; ++f) {
            const int tl = l * NF + f;
            const int s  = tl & 1;
            const bf16x8 bv0 = pre0[s];
            const bf16x8 bv1 = pre1[s];

            // issue prefetch for tl+2 (clamped; crosses layer boundary naturally)
            {
                int pf = tl + 2; if (pf > NFT - 1) pf = NFT - 1;
                const unsigned short* p = wq + pf * 8192;
                pre0[s] = *(const bf16x8*)p;
                pre1[s] = *(const bf16x8*)(p + 4096);
            }

            const f32x4* xp = (const f32x4*)&xf32[f * 64 + q * 4];
            #pragma unroll
            for (int mt = 0; mt < 4; ++mt) {
                f32x4 sv = __builtin_amdgcn_mfma_f32_16x16x32_bf16(a[0][mt], bv0, z,  0, 0, 0);
                sv       = __builtin_amdgcn_mfma_f32_16x16x32_bf16(a[1][mt], bv1, sv, 0, 0, 0);
                const f32x4 xr = xp[mt * 4];   // +16 floats per m-tile
                #pragma unroll
                for (int r = 0; r < 4; ++r)
                    cur[mt][r] = fmaf(xr[r], sv[r], cur[mt][r]);
            }
        }

        // ---------------- epilogue for layer l ----------------
        const float bias = biasl[l * LCH + nc];
        float v[4][4];
        #pragma unroll
        for (int mt = 0; mt < 4; ++mt)
            #pragma unroll
            for (int r = 0; r < 4; ++r)
                v[mt][r] = fmaxf(cur[mt][r] + bias, 0.f);

        if (l < 2 && w < 4) {
            // h channels (nc < 64): write next layer's h (C row = q*4+r)
            #pragma unroll
            for (int mt = 0; mt < 4; ++mt)
                #pragma unroll
                for (int r = 0; r < 4; ++r)
                    hfrag[((nc >> 3) * 64 + mt * 16 + q * 4 + r) * 8 + (nc & 7)] =
                        f2bf_rne(v[mt][r]);
        } else {
            // direct channels: reduce over d (= q*4+r) and store
            // l==0: nc 64..127 -> out 0..63 ; l==1: nc 64..127 -> out 64..127 ;
            // l==2: nc 0..127 -> out 128..255
            const int outcol = (l == 0) ? nc - 64 : (l == 1) ? nc : 128 + nc;
            #pragma unroll
            for (int mt = 0; mt < 4; ++mt) {
                float sacc = v[mt][0] + v[mt][1] + v[mt][2] + v[mt][3];
                sacc += __shfl_xor(sacc, 16, 64);
                sacc += __shfl_xor(sacc, 32, 64);
                if (lane < 16) out[(bb + mt) * 256 + outcol] = sacc;
            }
        }
        if (l < 2) __syncthreads();   // h writes visible before next A-hoist
    }
}

extern "C" void kernel_launch(void* const* d_in, const int* in_sizes, int n_in,
                              void* d_out, int out_size, void* d_ws, size_t ws_size,
                              hipStream_t stream) {
    const float* x  = (const float*)d_in[0];
    const float* W0 = (const float*)d_in[1];
    const float* W1 = (const float*)d_in[2];
    const float* W2 = (const float*)d_in[3];
    const float* b0 = (const float*)d_in[4];
    const float* b1 = (const float*)d_in[5];
    const float* b2 = (const float*)d_in[6];
    float* out = (float*)d_out;
    unsigned short* wt = (unsigned short*)d_ws;  // 117*8192*2 B = 1.87 MB

    const int prep_threads = NFT * 1024;         // 119808
    cin_prep<<<(prep_threads + 255) / 256, 256, 0, stream>>>(W0, W1, W2, wt);
    cin_mfma<<<256, 512, 0, stream>>>(x, wt, b0, b1, b2, out);
}

// Round 5
// 259.413 us; speedup vs baseline: 1.0169x; 1.0169x over previous
//
#include <hip/hip_runtime.h>

// CIN fused 3-layer, bf16 MFMA, barrier-free K-loop version (R5 = R4 + VGPR cap fix).
// cur[sl,n] = sum_f x_f[sl] * S_f[sl,n],  S_f = sum_g h_g[sl] * W[f*64+g, n].
// Wave w (0..7) owns n-tile w (16 channels) and ALL 4 m-tiles (64 slices);
// B-frags are wave-private -> streamed L2->VGPR with global_load_dwordx4,
// depth-2 register rotation, NO barrier inside the f-loop.
// R4 bug: bare __launch_bounds__(512) capped VGPRs at 128 -> spills -> 357 MB
// scratch writes, HBM-bound. Fix: __launch_bounds__(512, 2) = 1 block/CU,
// cap 256 VGPRs, no spills.
//
// wt layout (prep output), tile tl = l*39+f (layer0 g zero-padded):
//   wt[tl*8192 + ((ks*4 + q)*128 + n)*8 + j] = bf16(W_l[f*64 + ks*32+q*8+j][n])

#define NF     39
#define LCH    128
#define NLAYER 3
#define NFT    (NLAYER * NF)   // 117 f-tiles

typedef __bf16        bf16x8 __attribute__((ext_vector_type(8)));
typedef unsigned int  uint4v __attribute__((ext_vector_type(4)));
typedef float         f32x4  __attribute__((ext_vector_type(4)));

__device__ __forceinline__ unsigned short f2bf_rne(float f) {
    unsigned u = __float_as_uint(f);
    u += 0x7fffu + ((u >> 16) & 1u);
    return (unsigned short)(u >> 16);
}

// ---------------- prep: W fp32 -> bf16 frag-ready tiles in ws ----------------
__global__ void cin_prep(const float* __restrict__ W0,
                         const float* __restrict__ W1,
                         const float* __restrict__ W2,
                         unsigned short* __restrict__ wt)
{
    const int t = blockIdx.x * blockDim.x + threadIdx.x; // ((tl*2+ks)*4+q)*128 + n
    if (t >= NFT * 1024) return;
    const int n  = t & 127;
    const int q  = (t >> 7) & 3;
    const int ks = (t >> 9) & 1;
    const int tl = t >> 10;
    const int l  = tl / NF;
    const int f  = tl - l * NF;
    const float* W = (l == 0) ? W0 : (l == 1) ? W1 : W2;

    unsigned short v[8];
    #pragma unroll
    for (int j = 0; j < 8; ++j) {
        const int g = ks * 32 + q * 8 + j;
        float w = 0.0f;
        if (l == 0) { if (g < NF) w = W[(f * NF + g) * LCH + n]; }
        else        { w = W[(f * 64 + g) * LCH + n]; }
        v[j] = f2bf_rne(w);
    }
    uint4v pv;
    #pragma unroll
    for (int i = 0; i < 4; ++i)
        pv[i] = (unsigned)v[2 * i] | ((unsigned)v[2 * i + 1] << 16);
    ((uint4v*)wt)[t] = pv;   // 16B coalesced
}

// ---------------- main ----------------
__global__ __launch_bounds__(512, 2) void cin_mfma(
    const float* __restrict__ x,
    const unsigned short* __restrict__ wt,
    const float* __restrict__ b0p,
    const float* __restrict__ b1p,
    const float* __restrict__ b2p,
    float* __restrict__ out)
{
    __shared__ __align__(16) unsigned short hfrag[8 * 64 * 8];  // [gblk][sl][j], 8 KB
    __shared__ float xf32[NF * 64];                             // [f][sl] fp32
    __shared__ float biasl[NLAYER * LCH];

    const int tid  = threadIdx.x;
    const int lane = tid & 63;
    const int w    = tid >> 6;      // wave 0..7 = n-tile
    const int q    = lane >> 4;     // quad 0..3
    const int c    = lane & 15;
    const int nc   = w * 16 + c;    // this lane's output channel
    const int bb   = blockIdx.x * 4;

    // zero hfrag (covers layer-0 padding g in [39,64))
    {
        f32x4 z = {0.f, 0.f, 0.f, 0.f};
        ((f32x4*)hfrag)[tid] = z;   // 512*16B = 8 KB exactly
    }
    for (int t = tid; t < NLAYER * LCH; t += 512)
        biasl[t] = (t < 128) ? b0p[t] : (t < 256) ? b1p[t - 128] : b2p[t - 256];
    __syncthreads();

    // stage x (contiguous 2496 floats for this block's 4 b's)
    for (int i = tid; i < 4 * NF * 16; i += 512) {
        const float v = x[bb * (NF * 16) + i];
        const int lb = i / (NF * 16);
        const int r  = i - lb * (NF * 16);
        const int f  = r >> 4;
        const int d  = r & 15;
        const int sl = lb * 16 + d;
        xf32[f * 64 + sl] = v;
        hfrag[((f >> 3) * 64 + sl) * 8 + (f & 7)] = f2bf_rne(v);
    }

    // wave-private B pointer: lane (q,c) of wave w reads 16B at
    // wt + tl*8192 + (q*128 + nc)*8  (ks=0)  and +4096 shorts (ks=1)
    const unsigned short* wq = wt + (q * 128 + nc) * 8;

    // depth-2 register rotation, preloaded before the barrier (regs only)
    bf16x8 pre0[2], pre1[2];
    {
        const unsigned short* p0 = wq;             // tl = 0
        const unsigned short* p1 = wq + 8192;      // tl = 1
        pre0[0] = *(const bf16x8*)p0;  pre1[0] = *(const bf16x8*)(p0 + 4096);
        pre0[1] = *(const bf16x8*)p1;  pre1[1] = *(const bf16x8*)(p1 + 4096);
    }
    __syncthreads();   // x, hfrag, bias ready

    #pragma unroll
    for (int l = 0; l < NLAYER; ++l) {
        // hoist A-frags (h) for this layer: a[ks][mt]
        bf16x8 a[2][4];
        #pragma unroll
        for (int ks = 0; ks < 2; ++ks)
            #pragma unroll
            for (int mt = 0; mt < 4; ++mt)
                a[ks][mt] = *(const bf16x8*)&hfrag[((ks * 4 + q) * 64 + mt * 16 + c) * 8];

        f32x4 cur[4];
        #pragma unroll
        for (int mt = 0; mt < 4; ++mt) cur[mt] = f32x4{0.f, 0.f, 0.f, 0.f};
        const f32x4 z = {0.f, 0.f, 0.f, 0.f};

        #pragma unroll 2
        for (int f = 0; f < NF; ++f) {
            const int tl = l * NF + f;
            const int s  = tl & 1;
            const bf16x8 bv0 = pre0[s];
            const bf16x8 bv1 = pre1[s];

            // issue prefetch for tl+2 (clamped; crosses layer boundary naturally)
            {
                int pf = tl + 2; if (pf > NFT - 1) pf = NFT - 1;
                const unsigned short* p = wq + pf * 8192;
                pre0[s] = *(const bf16x8*)p;
                pre1[s] = *(const bf16x8*)(p + 4096);
            }

            const f32x4* xp = (const f32x4*)&xf32[f * 64 + q * 4];
            #pragma unroll
            for (int mt = 0; mt < 4; ++mt) {
                f32x4 sv = __builtin_amdgcn_mfma_f32_16x16x32_bf16(a[0][mt], bv0, z,  0, 0, 0);
                sv       = __builtin_amdgcn_mfma_f32_16x16x32_bf16(a[1][mt], bv1, sv, 0, 0, 0);
                const f32x4 xr = xp[mt * 4];   // +16 floats per m-tile
                #pragma unroll
                for (int r = 0; r < 4; ++r)
                    cur[mt][r] = fmaf(xr[r], sv[r], cur[mt][r]);
            }
        }

        // ---------------- epilogue for layer l ----------------
        const float bias = biasl[l * LCH + nc];
        float v[4][4];
        #pragma unroll
        for (int mt = 0; mt < 4; ++mt)
            #pragma unroll
            for (int r = 0; r < 4; ++r)
                v[mt][r] = fmaxf(cur[mt][r] + bias, 0.f);

        if (l < 2 && w < 4) {
            // h channels (nc < 64): write next layer's h (C row = q*4+r)
            #pragma unroll
            for (int mt = 0; mt < 4; ++mt)
                #pragma unroll
                for (int r = 0; r < 4; ++r)
                    hfrag[((nc >> 3) * 64 + mt * 16 + q * 4 + r) * 8 + (nc & 7)] =
                        f2bf_rne(v[mt][r]);
        } else {
            // direct channels: reduce over d (= q*4+r) and store
            // l==0: nc 64..127 -> out 0..63 ; l==1: nc 64..127 -> out 64..127 ;
            // l==2: nc 0..127 -> out 128..255
            const int outcol = (l == 0) ? nc - 64 : (l == 1) ? nc : 128 + nc;
            #pragma unroll
            for (int mt = 0; mt < 4; ++mt) {
                float sacc = v[mt][0] + v[mt][1] + v[mt][2] + v[mt][3];
                sacc += __shfl_xor(sacc, 16, 64);
                sacc += __shfl_xor(sacc, 32, 64);
                if (lane < 16) out[(bb + mt) * 256 + outcol] = sacc;
            }
        }
        if (l < 2) __syncthreads();   // h writes visible before next A-hoist
    }
}

extern "C" void kernel_launch(void* const* d_in, const int* in_sizes, int n_in,
                              void* d_out, int out_size, void* d_ws, size_t ws_size,
                              hipStream_t stream) {
    const float* x  = (const float*)d_in[0];
    const float* W0 = (const float*)d_in[1];
    const float* W1 = (const float*)d_in[2];
    const float* W2 = (const float*)d_in[3];
    const float* b0 = (const float*)d_in[4];
    const float* b1 = (const float*)d_in[5];
    const float* b2 = (const float*)d_in[6];
    float* out = (float*)d_out;
    unsigned short* wt = (unsigned short*)d_ws;  // 117*8192*2 B = 1.87 MB

    const int prep_threads = NFT * 1024;         // 119808
    cin_prep<<<(prep_threads + 255) / 256, 256, 0, stream>>>(W0, W1, W2, wt);
    cin_mfma<<<256, 512, 0, stream>>>(x, wt, b0, b1, b2, out);
}

// Round 6
// 116.783 us; speedup vs baseline: 2.2589x; 2.2213x over previous
//
#include <hip/hip_runtime.h>

// CIN fused 3-layer, bf16 MFMA, barrier-free K-loop (R6).
// cur[sl,n] = sum_f x_f[sl] * S_f[sl,n],  S_f = sum_g h_g[sl] * W[f*64+g, n].
// Wave w (0..7) owns n-tile w (16 channels) and ALL 4 m-tiles (64 slices);
// B-frags streamed L2->VGPR with plain dwordx4 loads, depth-2 rotation.
// R4/R5 bug: rotation arrays pre0[s]/pre1[s] with runtime s -> not SROA-able
// -> placed in scratch -> 357 MB HBM spill traffic. R6: scalar double-buffer
// variables (c0,c1 / n0,n1) rotated by value copy — no indexable arrays, no
// scratch, regardless of l-loop unrolling.
//
// wt layout (prep output), tile tl = l*39+f (layer0 g zero-padded):
//   wt[tl*8192 + ((ks*4 + q)*128 + n)*8 + j] = bf16(W_l[f*64 + ks*32+q*8+j][n])

#define NF     39
#define LCH    128
#define NLAYER 3
#define NFT    (NLAYER * NF)   // 117 f-tiles

typedef __bf16        bf16x8 __attribute__((ext_vector_type(8)));
typedef unsigned int  uint4v __attribute__((ext_vector_type(4)));
typedef float         f32x4  __attribute__((ext_vector_type(4)));

__device__ __forceinline__ unsigned short f2bf_rne(float f) {
    unsigned u = __float_as_uint(f);
    u += 0x7fffu + ((u >> 16) & 1u);
    return (unsigned short)(u >> 16);
}

// ---------------- prep: W fp32 -> bf16 frag-ready tiles in ws ----------------
__global__ void cin_prep(const float* __restrict__ W0,
                         const float* __restrict__ W1,
                         const float* __restrict__ W2,
                         unsigned short* __restrict__ wt)
{
    const int t = blockIdx.x * blockDim.x + threadIdx.x; // ((tl*2+ks)*4+q)*128 + n
    if (t >= NFT * 1024) return;
    const int n  = t & 127;
    const int q  = (t >> 7) & 3;
    const int ks = (t >> 9) & 1;
    const int tl = t >> 10;
    const int l  = tl / NF;
    const int f  = tl - l * NF;
    const float* W = (l == 0) ? W0 : (l == 1) ? W1 : W2;

    unsigned short v[8];
    #pragma unroll
    for (int j = 0; j < 8; ++j) {
        const int g = ks * 32 + q * 8 + j;
        float w = 0.0f;
        if (l == 0) { if (g < NF) w = W[(f * NF + g) * LCH + n]; }
        else        { w = W[(f * 64 + g) * LCH + n]; }
        v[j] = f2bf_rne(w);
    }
    uint4v pv;
    #pragma unroll
    for (int i = 0; i < 4; ++i)
        pv[i] = (unsigned)v[2 * i] | ((unsigned)v[2 * i + 1] << 16);
    ((uint4v*)wt)[t] = pv;   // 16B coalesced
}

// ---------------- main ----------------
__global__ __launch_bounds__(512, 2) void cin_mfma(
    const float* __restrict__ x,
    const unsigned short* __restrict__ wt,
    const float* __restrict__ b0p,
    const float* __restrict__ b1p,
    const float* __restrict__ b2p,
    float* __restrict__ out)
{
    __shared__ __align__(16) unsigned short hfrag[8 * 64 * 8];  // [gblk][sl][j], 8 KB
    __shared__ float xf32[NF * 64];                             // [f][sl] fp32
    __shared__ float biasl[NLAYER * LCH];

    const int tid  = threadIdx.x;
    const int lane = tid & 63;
    const int w    = tid >> 6;      // wave 0..7 = n-tile
    const int q    = lane >> 4;     // quad 0..3
    const int c    = lane & 15;
    const int nc   = w * 16 + c;    // this lane's output channel
    const int bb   = blockIdx.x * 4;

    // zero hfrag (covers layer-0 padding g in [39,64))
    {
        f32x4 z = {0.f, 0.f, 0.f, 0.f};
        ((f32x4*)hfrag)[tid] = z;   // 512*16B = 8 KB exactly
    }
    for (int t = tid; t < NLAYER * LCH; t += 512)
        biasl[t] = (t < 128) ? b0p[t] : (t < 256) ? b1p[t - 128] : b2p[t - 256];
    __syncthreads();

    // stage x (contiguous 2496 floats for this block's 4 b's)
    for (int i = tid; i < 4 * NF * 16; i += 512) {
        const float v = x[bb * (NF * 16) + i];
        const int lb = i / (NF * 16);
        const int r  = i - lb * (NF * 16);
        const int f  = r >> 4;
        const int d  = r & 15;
        const int sl = lb * 16 + d;
        xf32[f * 64 + sl] = v;
        hfrag[((f >> 3) * 64 + sl) * 8 + (f & 7)] = f2bf_rne(v);
    }

    // wave-private B pointer: lane (q,c) of wave w reads 16B at
    // wt + tl*8192 + (q*128 + nc)*8  (ks=0)  and +4096 shorts (ks=1)
    const unsigned short* wq = wt + (q * 128 + nc) * 8;

    // depth-2 rotation in plain scalars: c* = tile tl, n* = tile tl+1
    bf16x8 c0 = *(const bf16x8*)(wq);
    bf16x8 c1 = *(const bf16x8*)(wq + 4096);
    bf16x8 n0 = *(const bf16x8*)(wq + 8192);
    bf16x8 n1 = *(const bf16x8*)(wq + 8192 + 4096);

    __syncthreads();   // x, hfrag, bias ready

    #pragma unroll 1
    for (int l = 0; l < NLAYER; ++l) {
        // hoist A-frags (h) for this layer: a[ks][mt] (literal indices only)
        bf16x8 a[2][4];
        #pragma unroll
        for (int ks = 0; ks < 2; ++ks)
            #pragma unroll
            for (int mt = 0; mt < 4; ++mt)
                a[ks][mt] = *(const bf16x8*)&hfrag[((ks * 4 + q) * 64 + mt * 16 + c) * 8];

        f32x4 cur[4];
        #pragma unroll
        for (int mt = 0; mt < 4; ++mt) cur[mt] = f32x4{0.f, 0.f, 0.f, 0.f};
        const f32x4 z = {0.f, 0.f, 0.f, 0.f};

        #pragma unroll 1
        for (int f = 0; f < NF; ++f) {
            const bf16x8 bv0 = c0;
            const bf16x8 bv1 = c1;

            #pragma unroll
            for (int mt = 0; mt < 4; ++mt) {
                f32x4 sv = __builtin_amdgcn_mfma_f32_16x16x32_bf16(a[0][mt], bv0, z,  0, 0, 0);
                sv       = __builtin_amdgcn_mfma_f32_16x16x32_bf16(a[1][mt], bv1, sv, 0, 0, 0);
                const f32x4 xr = *(const f32x4*)&xf32[f * 64 + mt * 16 + q * 4];
                #pragma unroll
                for (int r = 0; r < 4; ++r)
                    cur[mt][r] = fmaf(xr[r], sv[r], cur[mt][r]);
            }

            // rotate and prefetch tl+2 (clamped)
            c0 = n0; c1 = n1;
            int pf = l * NF + f + 2; if (pf > NFT - 1) pf = NFT - 1;
            const unsigned short* p = wq + (size_t)pf * 8192;
            n0 = *(const bf16x8*)p;
            n1 = *(const bf16x8*)(p + 4096);
        }

        // ---------------- epilogue for layer l ----------------
        const float bias = biasl[l * LCH + nc];
        float v[4][4];
        #pragma unroll
        for (int mt = 0; mt < 4; ++mt)
            #pragma unroll
            for (int r = 0; r < 4; ++r)
                v[mt][r] = fmaxf(cur[mt][r] + bias, 0.f);

        if (l < 2 && w < 4) {
            // h channels (nc < 64): write next layer's h (C row = q*4+r)
            #pragma unroll
            for (int mt = 0; mt < 4; ++mt)
                #pragma unroll
                for (int r = 0; r < 4; ++r)
                    hfrag[((nc >> 3) * 64 + mt * 16 + q * 4 + r) * 8 + (nc & 7)] =
                        f2bf_rne(v[mt][r]);
        } else {
            // direct channels: reduce over d (= q*4+r) and store
            // l==0: nc 64..127 -> out 0..63 ; l==1: nc 64..127 -> out 64..127 ;
            // l==2: nc 0..127 -> out 128..255
            const int outcol = (l == 0) ? nc - 64 : (l == 1) ? nc : 128 + nc;
            #pragma unroll
            for (int mt = 0; mt < 4; ++mt) {
                float sacc = v[mt][0] + v[mt][1] + v[mt][2] + v[mt][3];
                sacc += __shfl_xor(sacc, 16, 64);
                sacc += __shfl_xor(sacc, 32, 64);
                if (lane < 16) out[(bb + mt) * 256 + outcol] = sacc;
            }
        }
        if (l < 2) __syncthreads();   // h writes visible before next A-hoist
    }
}

extern "C" void kernel_launch(void* const* d_in, const int* in_sizes, int n_in,
                              void* d_out, int out_size, void* d_ws, size_t ws_size,
                              hipStream_t stream) {
    const float* x  = (const float*)d_in[0];
    const float* W0 = (const float*)d_in[1];
    const float* W1 = (const float*)d_in[2];
    const float* W2 = (const float*)d_in[3];
    const float* b0 = (const float*)d_in[4];
    const float* b1 = (const float*)d_in[5];
    const float* b2 = (const float*)d_in[6];
    float* out = (float*)d_out;
    unsigned short* wt = (unsigned short*)d_ws;  // 117*8192*2 B = 1.87 MB

    const int prep_threads = NFT * 1024;         // 119808
    cin_prep<<<(prep_threads + 255) / 256, 256, 0, stream>>>(W0, W1, W2, wt);
    cin_mfma<<<256, 512, 0, stream>>>(x, wt, b0, b1, b2, out);
}